// Round 17
// baseline (186.061 us; speedup 1.0000x reference)
//
#include <hip/hip_runtime.h>

#define DIM 1024
#define NHEADS 16
#define HD 64
#define SEQ 2048
#define BATCH 4
#define MROWS (BATCH * SEQ)  /* 8192 */
#define N3 (3 * DIM)         /* 3072 */
#define SCALE 0.125f
#define LOG2E 1.4426950408889634f
#define SM_C (SCALE * LOG2E) /* scores -> log2 domain */
#define SMAX 16.0f           /* static softmax max (log2 domain) */

typedef __attribute__((ext_vector_type(8))) __bf16 bf16x8;
typedef __attribute__((ext_vector_type(4))) __bf16 bf16x4;
typedef __attribute__((ext_vector_type(4))) float f32x4;

#define MFMA16(a, b, c) __builtin_amdgcn_mfma_f32_16x16x32_bf16((a), (b), (c), 0, 0, 0)

#define GLDS16(g, l)                                                        \
  __builtin_amdgcn_global_load_lds(                                         \
      (const __attribute__((address_space(1))) void*)(g),                   \
      (__attribute__((address_space(3))) void*)(l), 16, 0, 0)

__device__ __forceinline__ unsigned short f2bf(float f) {
  union { float f; unsigned u; } v;
  v.f = f;
  unsigned r = v.u + 0x7fffu + ((v.u >> 16) & 1u);
  return (unsigned short)(r >> 16);
}

__device__ __forceinline__ float exp2_hw(float x) {
  float r;
  asm("v_exp_f32 %0, %1" : "=v"(r) : "v"(x));
  return r;
}

/* ---------------- fused prep kernel ---------------- */

__device__ __forceinline__ void tcast_tile(const float* __restrict__ in,
                                           unsigned short* __restrict__ out,
                                           int K, int N, int bx, int by,
                                           int t) {
  __shared__ float tile[32][33];
  int c = t & 31, r8 = t >> 5;
  int n0 = bx * 32, k0 = by * 32;
#pragma unroll
  for (int i = 0; i < 4; ++i) {
    int kr = r8 + i * 8;
    tile[kr][c] = in[(size_t)(k0 + kr) * N + n0 + c];
  }
  __syncthreads();
#pragma unroll
  for (int i = 0; i < 4; ++i) {
    int nr = r8 + i * 8;
    out[(size_t)(n0 + nr) * K + k0 + c] = f2bf(tile[c][nr]);
  }
}

__global__ void prep_kernel(const float* __restrict__ x,
                            unsigned short* __restrict__ xb,
                            const float* __restrict__ wqkv,
                            unsigned short* __restrict__ wqkvT,
                            const float* __restrict__ wproj,
                            unsigned short* __restrict__ wprojT) {
  const int bid = blockIdx.x, t = threadIdx.x;
  if (bid < 8192) {
    int i = bid * 256 + t;
    float4 v = ((const float4*)x)[i];
    ushort4 o;
    o.x = f2bf(v.x); o.y = f2bf(v.y); o.z = f2bf(v.z); o.w = f2bf(v.w);
    ((ushort4*)xb)[i] = o;
  } else if (bid < 11264) {
    int local = bid - 8192;
    tcast_tile(wqkv, wqkvT, DIM, N3, local % 96, local / 96, t);
  } else {
    int local = bid - 11264;
    tcast_tile(wproj, wprojT, DIM, DIM, local % 32, local / 32, t);
  }
}

/* ---------------- QKV GEMM (128x128, BK=64, swizzled) --------------------
   Epilogue: V third packed as ushort4 (r=0..3 are 4 consecutive s in
   Vt[d][s]) -> 8B coalesced stores instead of 2B scatter. Q/K scalar. */

__global__ __launch_bounds__(256, 3)
void gemm_qkv_kernel(const unsigned short* __restrict__ A,
                     const unsigned short* __restrict__ Bt,
                     unsigned short* __restrict__ Qb,
                     unsigned short* __restrict__ Kb,
                     unsigned short* __restrict__ Vt) {
  __shared__ __align__(16) unsigned short As[128 * 64];
  __shared__ __align__(16) unsigned short Bs[128 * 64];
  int t = threadIdx.x;
  int w = t >> 6, l = t & 63;
  int lane16 = l & 15, lhi = l >> 4;
  int mbase = blockIdx.y * 128, nbase = blockIdx.x * 128;
  int wm = (w >> 1) * 64, wn = (w & 1) * 64;

  const int srow = t >> 3;                       /* 0..31 */
  const int sslot = (t & 7) ^ ((t >> 3) & 7);    /* 3-bit key = row&7 */
  const unsigned short* Ag = A + (size_t)(mbase + srow) * 1024 + sslot * 8;
  const unsigned short* Bg = Bt + (size_t)(nbase + srow) * 1024 + sslot * 8;

  const int sl0 = ((lhi ^ (lane16 & 7)) << 4);
  const char* Ard = (const char*)As + (wm + lane16) * 128;
  const char* Brd = (const char*)Bs + (wn + lane16) * 128;

  f32x4 acc[4][4];
  f32x4 z4 = {0.f, 0.f, 0.f, 0.f};
#pragma unroll
  for (int i = 0; i < 4; ++i)
#pragma unroll
    for (int j = 0; j < 4; ++j) acc[i][j] = z4;

  for (int kt = 0; kt < 1024; kt += 64) {
#pragma unroll
    for (int i = 0; i < 4; ++i) {
      GLDS16(Ag + (size_t)(i * 32) * 1024 + kt, (char*)As + i * 4096 + w * 1024);
      GLDS16(Bg + (size_t)(i * 32) * 1024 + kt, (char*)Bs + i * 4096 + w * 1024);
    }
    __syncthreads();
#pragma unroll
    for (int kh = 0; kh < 2; ++kh) {
      const int so = sl0 ^ (kh << 6);
      bf16x8 af[4], bfr[4];
#pragma unroll
      for (int mi = 0; mi < 4; ++mi)
        af[mi] = *(const bf16x8*)(Ard + mi * 2048 + so);
#pragma unroll
      for (int ni = 0; ni < 4; ++ni)
        bfr[ni] = *(const bf16x8*)(Brd + ni * 2048 + so);
#pragma unroll
      for (int mi = 0; mi < 4; ++mi)
#pragma unroll
        for (int ni = 0; ni < 4; ++ni)
          acc[mi][ni] = MFMA16(af[mi], bfr[ni], acc[mi][ni]);
    }
    __syncthreads();
  }

#pragma unroll
  for (int mi = 0; mi < 4; ++mi) {
#pragma unroll
    for (int ni = 0; ni < 4; ++ni) {
      const int gcol = nbase + wn + ni * 16 + lane16;
      if (gcol < 2048) {
#pragma unroll
        for (int r = 0; r < 4; ++r) {
          int grow = mbase + wm + mi * 16 + (lhi << 2) + r;
          int b = grow >> 11, s = grow & 2047;
          unsigned short val = f2bf(acc[mi][ni][r]);
          if (gcol < 1024) {
            int h = gcol >> 6, d = gcol & 63;
            Qb[((size_t)(b * 16 + h) * 2048 + s) * 64 + d] = val;
          } else {
            int n2 = gcol - 1024;
            int h = n2 >> 6, d = n2 & 63;
            Kb[((size_t)(b * 16 + h) * 2048 + s) * 64 + d] = val;
          }
        }
      } else {
        int grow0 = mbase + wm + mi * 16 + (lhi << 2);
        int b = grow0 >> 11, s = grow0 & 2047;
        int n2 = gcol - 2048;
        int h = n2 >> 6, d = n2 & 63;
        ushort4 v4;
        v4.x = f2bf(acc[mi][ni][0]);
        v4.y = f2bf(acc[mi][ni][1]);
        v4.z = f2bf(acc[mi][ni][2]);
        v4.w = f2bf(acc[mi][ni][3]);
        *(ushort4*)&Vt[((size_t)(b * 16 + h) * 64 + d) * 2048 + s] = v4;
      }
    }
  }
}

/* ---------------- flash attention (r14 proven best) ---------------------
   grid 512 blocks (XCD-chunk swizzled), 512 threads = 8 waves.
   Block: 256 q-rows of one (b,h); wave: 32 q-rows. KVBLK = 64.
   K/V staged via global_load_lds, double-buffered, 3-bit XOR swizzle
   (both-sides). Ps [8][32][64] exact-128B rows, same XOR write+read.
   Static-max softmax: p = exp2(s*SM_C - 16).
   NOTE (r15 lesson): do NOT hoist V ds_reads before the Ps ds_writes —
   LDS queue is FIFO, lengthening the pa-read lgkmcnt wait (−3 us). */

__global__ __launch_bounds__(512, 4)
void attn_kernel(const unsigned short* __restrict__ Qb,
                 const unsigned short* __restrict__ Kb,
                 const unsigned short* __restrict__ Vt,
                 unsigned short* __restrict__ attn) {
  __shared__ __align__(16) unsigned short Ks[2][4096]; /* [64 rows][128B] swz */
  __shared__ __align__(16) unsigned short Vs[2][4096]; /* [64 drows][128B] swz */
  __shared__ __align__(16) unsigned short Ps[8][32][64]; /* swizzled rows */

  const int t = threadIdx.x, wv = t >> 6, l = t & 63;
  const int lane16 = l & 15, lhi = l >> 4;

  /* bijective XCD-chunk swizzle: 512 blocks, 8 XCDs, 64 per chunk */
  const int bid = blockIdx.x;
  const int nid = (bid & 7) * 64 + (bid >> 3);
  const int qg = nid & 7, h = (nid >> 3) & 15, b = nid >> 7;

  const unsigned short* Qp = Qb + (size_t)(b * NHEADS + h) * SEQ * HD;
  const unsigned short* Kp = Kb + (size_t)(b * NHEADS + h) * SEQ * HD;
  const unsigned short* Vp = Vt + (size_t)(b * NHEADS + h) * HD * SEQ;

  const int q0 = qg * 256 + wv * 32;

  bf16x8 qa[2][2];
#pragma unroll
  for (int mi = 0; mi < 2; ++mi)
#pragma unroll
    for (int kh = 0; kh < 2; ++kh)
      qa[mi][kh] = *(const bf16x8*)(Qp + (size_t)(q0 + mi * 16 + lane16) * HD +
                                    kh * 32 + lhi * 8);

  const int srow = t >> 3; /* 0..63 */
  const unsigned short* kg = Kp + srow * HD + (((t & 7) ^ ((t >> 5) & 7)) * 8);
  const unsigned short* vg =
      Vp + (size_t)srow * SEQ + (((t & 7) ^ ((t >> 3) & 7)) * 8);

  const int key = lane16 & 7;
  const int off0 = (lhi ^ key) << 4;
  const int off1 = off0 ^ 64;
  const char* krd = (const char*)&Ks[0][0] + lane16 * 512;
  const char* vrd = (const char*)&Vs[0][0] + lane16 * 128;

  /* Ps addressing (swizzled): write base half-slot, read slot key */
  char* psbase = (char*)&Ps[wv][0][0];
  const int wsl = ((lane16 >> 1) << 4) + ((lane16 & 1) << 3);
  const int rsl = key << 4;

  f32x4 z4 = {0.f, 0.f, 0.f, 0.f};
  f32x4 o[2][4];
  float lsum[2][4];
#pragma unroll
  for (int mi = 0; mi < 2; ++mi)
#pragma unroll
    for (int nd = 0; nd < 4; ++nd) o[mi][nd] = z4;
#pragma unroll
  for (int mi = 0; mi < 2; ++mi)
#pragma unroll
    for (int r = 0; r < 4; ++r) lsum[mi][r] = 0.f;

  GLDS16(kg, (char*)&Ks[0][0] + wv * 1024);
  GLDS16(vg, (char*)&Vs[0][0] + wv * 1024);
  __syncthreads();

  int cur = 0;
  for (int ti = 0; ti < SEQ / 64; ++ti) {
    if (ti < SEQ / 64 - 1) {
      const int kb = (ti + 1) * 64;
      GLDS16(kg + (size_t)kb * HD, (char*)&Ks[cur ^ 1][0] + wv * 1024);
      GLDS16(vg + kb, (char*)&Vs[cur ^ 1][0] + wv * 1024);
    }

    /* ---- QK^T ---- */
    const char* kp = krd + cur * 8192;
    bf16x8 kf[4][2];
#pragma unroll
    for (int ni = 0; ni < 4; ++ni) {
      kf[ni][0] = *(const bf16x8*)(kp + ni * 128 + off0);
      kf[ni][1] = *(const bf16x8*)(kp + ni * 128 + off1);
    }
#pragma unroll
    for (int mi = 0; mi < 2; ++mi) {
      f32x4 s[4];
#pragma unroll
      for (int ni = 0; ni < 4; ++ni) {
        f32x4 a = MFMA16(qa[mi][0], kf[ni][0], z4);
        s[ni] = MFMA16(qa[mi][1], kf[ni][1], a);
      }
#pragma unroll
      for (int r = 0; r < 4; ++r) {
        float p0 = exp2_hw(__builtin_fmaf(s[0][r], SM_C, -SMAX));
        float p1 = exp2_hw(__builtin_fmaf(s[1][r], SM_C, -SMAX));
        float p2 = exp2_hw(__builtin_fmaf(s[2][r], SM_C, -SMAX));
        float p3 = exp2_hw(__builtin_fmaf(s[3][r], SM_C, -SMAX));
        lsum[mi][r] += (p0 + p1) + (p2 + p3);
        bf16x4 pk;
        pk[0] = (__bf16)p0; pk[1] = (__bf16)p1;
        pk[2] = (__bf16)p2; pk[3] = (__bf16)p3;
        const int row = mi * 16 + (lhi << 2) + r;
        const int rk = ((lhi << 2) + r) & 7;
        *(bf16x4*)(psbase + row * 128 + (wsl ^ (rk << 4))) = pk;
      }
    }

    /* ---- PV ---- */
    bf16x8 pa[2][2];
#pragma unroll
    for (int mi = 0; mi < 2; ++mi)
#pragma unroll
      for (int kvh = 0; kvh < 2; ++kvh)
        pa[mi][kvh] = *(const bf16x8*)(psbase + (mi * 16 + lane16) * 128 +
                                       ((((kvh << 2) | lhi) << 4) ^ rsl));
    const char* vp2 = vrd + cur * 8192;
#pragma unroll
    for (int nd = 0; nd < 4; ++nd) {
      bf16x8 v0 = *(const bf16x8*)(vp2 + nd * 2048 + off0);
      bf16x8 v1 = *(const bf16x8*)(vp2 + nd * 2048 + off1);
#pragma unroll
      for (int mi = 0; mi < 2; ++mi) {
        o[mi][nd] = MFMA16(pa[mi][0], v0, o[mi][nd]);
        o[mi][nd] = MFMA16(pa[mi][1], v1, o[mi][nd]);
      }
    }
    __syncthreads();
    cur ^= 1;
  }

#pragma unroll
  for (int mi = 0; mi < 2; ++mi)
#pragma unroll
    for (int r = 0; r < 4; ++r) {
      float ls = lsum[mi][r];
      ls += __shfl_xor(ls, 1);
      ls += __shfl_xor(ls, 2);
      ls += __shfl_xor(ls, 4);
      ls += __shfl_xor(ls, 8);
      lsum[mi][r] = 1.0f / ls;
    }
  size_t orow_base = (size_t)b * SEQ;
#pragma unroll
  for (int mi = 0; mi < 2; ++mi)
#pragma unroll
    for (int nd = 0; nd < 4; ++nd)
#pragma unroll
      for (int r = 0; r < 4; ++r) {
        int row = q0 + mi * 16 + (lhi << 2) + r;
        attn[(orow_base + row) * DIM + h * HD + nd * 16 + lane16] =
            f2bf(o[mi][nd][r] * lsum[mi][r]);
      }
}

/* ---------------- out projection: out = A(8192x1024)*Bt(1024x1024)^T + bias */

__global__ __launch_bounds__(256, 3)
void gemm_proj_kernel(const unsigned short* __restrict__ A,
                      const unsigned short* __restrict__ Bt,
                      const float* __restrict__ bias,
                      float* __restrict__ out) {
  __shared__ __align__(16) unsigned short Asp[128 * 64];
  __shared__ __align__(16) unsigned short Bsp[128 * 64];
  int t = threadIdx.x;
  int w = t >> 6, l = t & 63;
  int lane16 = l & 15, lhi = l >> 4;
  int mbase = blockIdx.y * 128, nbase = blockIdx.x * 128;
  int wm = (w >> 1) * 64, wn = (w & 1) * 64;

  const int srow = t >> 3;
  const int sslot = (t & 7) ^ ((t >> 3) & 7);
  const unsigned short* Ag = A + (size_t)(mbase + srow) * 1024 + sslot * 8;
  const unsigned short* Bg = Bt + (size_t)(nbase + srow) * 1024 + sslot * 8;

  const int sl0 = ((lhi ^ (lane16 & 7)) << 4);
  const char* Ard = (const char*)Asp + (wm + lane16) * 128;
  const char* Brd = (const char*)Bsp + (wn + lane16) * 128;

  f32x4 acc[4][4];
  f32x4 z4 = {0.f, 0.f, 0.f, 0.f};
#pragma unroll
  for (int i = 0; i < 4; ++i)
#pragma unroll
    for (int j = 0; j < 4; ++j) acc[i][j] = z4;

  for (int kt = 0; kt < 1024; kt += 64) {
#pragma unroll
    for (int i = 0; i < 4; ++i) {
      GLDS16(Ag + (size_t)(i * 32) * 1024 + kt, (char*)Asp + i * 4096 + w * 1024);
      GLDS16(Bg + (size_t)(i * 32) * 1024 + kt, (char*)Bsp + i * 4096 + w * 1024);
    }
    __syncthreads();
#pragma unroll
    for (int kh = 0; kh < 2; ++kh) {
      const int so = sl0 ^ (kh << 6);
      bf16x8 af[4], bfr[4];
#pragma unroll
      for (int mi = 0; mi < 4; ++mi)
        af[mi] = *(const bf16x8*)(Ard + mi * 2048 + so);
#pragma unroll
      for (int ni = 0; ni < 4; ++ni)
        bfr[ni] = *(const bf16x8*)(Brd + ni * 2048 + so);
#pragma unroll
      for (int mi = 0; mi < 4; ++mi)
#pragma unroll
        for (int ni = 0; ni < 4; ++ni)
          acc[mi][ni] = MFMA16(af[mi], bfr[ni], acc[mi][ni]);
    }
    __syncthreads();
  }

#pragma unroll
  for (int mi = 0; mi < 4; ++mi) {
#pragma unroll
    for (int ni = 0; ni < 4; ++ni) {
#pragma unroll
      for (int r = 0; r < 4; ++r) {
        int grow = mbase + wm + mi * 16 + (lhi << 2) + r;
        int gcol = nbase + wn + ni * 16 + lane16;
        out[(size_t)grow * 1024 + gcol] = acc[mi][ni][r] + bias[gcol];
      }
    }
  }
}

/* ---------------- launch ---------------- */

extern "C" void kernel_launch(void* const* d_in, const int* in_sizes, int n_in,
                              void* d_out, int out_size, void* d_ws,
                              size_t ws_size, hipStream_t stream) {
  const float* x = (const float*)d_in[0];
  const float* w_qkv = (const float*)d_in[1];
  const float* w_proj = (const float*)d_in[2];
  const float* b_proj = (const float*)d_in[3];
  float* out = (float*)d_out;
  char* ws = (char*)d_ws;

  unsigned short* xb = (unsigned short*)(ws);
  unsigned short* attnb = (unsigned short*)(ws);
  unsigned short* wqkvT = (unsigned short*)(ws + (16ull << 20));
  unsigned short* wprojT = (unsigned short*)(ws + (22ull << 20));
  unsigned short* Qb = (unsigned short*)(ws + (24ull << 20));
  unsigned short* Kb = (unsigned short*)(ws + (40ull << 20));
  unsigned short* Vt = (unsigned short*)(ws + (56ull << 20));

  prep_kernel<<<12288, 256, 0, stream>>>(x, xb, w_qkv, wqkvT, w_proj, wprojT);
  gemm_qkv_kernel<<<dim3(N3 / 128, MROWS / 128), 256, 0, stream>>>(xb, wqkvT, Qb, Kb, Vt);
  attn_kernel<<<512, 512, 0, stream>>>(Qb, Kb, Vt, attnb);
  gemm_proj_kernel<<<dim3(DIM / 128, MROWS / 128), 256, 0, stream>>>(attnb, wprojT, b_proj, out);
}

// Round 18
// 182.764 us; speedup vs baseline: 1.0180x; 1.0180x over previous
//
#include <hip/hip_runtime.h>

#define DIM 1024
#define NHEADS 16
#define HD 64
#define SEQ 2048
#define BATCH 4
#define MROWS (BATCH * SEQ)  /* 8192 */
#define N3 (3 * DIM)         /* 3072 */
#define SCALE 0.125f
#define LOG2E 1.4426950408889634f
#define SM_C (SCALE * LOG2E) /* scores -> log2 domain */
#define SMAX 16.0f           /* static softmax max (log2 domain) */

typedef __attribute__((ext_vector_type(8))) __bf16 bf16x8;
typedef __attribute__((ext_vector_type(4))) __bf16 bf16x4;
typedef __attribute__((ext_vector_type(4))) float f32x4;

#define MFMA16(a, b, c) __builtin_amdgcn_mfma_f32_16x16x32_bf16((a), (b), (c), 0, 0, 0)

#define GLDS16(g, l)                                                        \
  __builtin_amdgcn_global_load_lds(                                         \
      (const __attribute__((address_space(1))) void*)(g),                   \
      (__attribute__((address_space(3))) void*)(l), 16, 0, 0)

__device__ __forceinline__ unsigned short f2bf(float f) {
  union { float f; unsigned u; } v;
  v.f = f;
  unsigned r = v.u + 0x7fffu + ((v.u >> 16) & 1u);
  return (unsigned short)(r >> 16);
}

__device__ __forceinline__ float exp2_hw(float x) {
  float r;
  asm("v_exp_f32 %0, %1" : "=v"(r) : "v"(x));
  return r;
}

/* ---------------- fused prep kernel ---------------- */

__device__ __forceinline__ void tcast_tile(const float* __restrict__ in,
                                           unsigned short* __restrict__ out,
                                           int K, int N, int bx, int by,
                                           int t) {
  __shared__ float tile[32][33];
  int c = t & 31, r8 = t >> 5;
  int n0 = bx * 32, k0 = by * 32;
#pragma unroll
  for (int i = 0; i < 4; ++i) {
    int kr = r8 + i * 8;
    tile[kr][c] = in[(size_t)(k0 + kr) * N + n0 + c];
  }
  __syncthreads();
#pragma unroll
  for (int i = 0; i < 4; ++i) {
    int nr = r8 + i * 8;
    out[(size_t)(n0 + nr) * K + k0 + c] = f2bf(tile[c][nr]);
  }
}

__global__ void prep_kernel(const float* __restrict__ x,
                            unsigned short* __restrict__ xb,
                            const float* __restrict__ wqkv,
                            unsigned short* __restrict__ wqkvT,
                            const float* __restrict__ wproj,
                            unsigned short* __restrict__ wprojT) {
  const int bid = blockIdx.x, t = threadIdx.x;
  if (bid < 8192) {
    int i = bid * 256 + t;
    float4 v = ((const float4*)x)[i];
    ushort4 o;
    o.x = f2bf(v.x); o.y = f2bf(v.y); o.z = f2bf(v.z); o.w = f2bf(v.w);
    ((ushort4*)xb)[i] = o;
  } else if (bid < 11264) {
    int local = bid - 8192;
    tcast_tile(wqkv, wqkvT, DIM, N3, local % 96, local / 96, t);
  } else {
    int local = bid - 11264;
    tcast_tile(wproj, wprojT, DIM, DIM, local % 32, local / 32, t);
  }
}

/* ---------------- QKV GEMM (128x128, BK=64, swizzled) --------------------
   Epilogue: V third packed as ushort4 (r=0..3 are 4 consecutive s in
   Vt[d][s]) -> 8B coalesced stores instead of 2B scatter. Q/K scalar. */

__global__ __launch_bounds__(256, 3)
void gemm_qkv_kernel(const unsigned short* __restrict__ A,
                     const unsigned short* __restrict__ Bt,
                     unsigned short* __restrict__ Qb,
                     unsigned short* __restrict__ Kb,
                     unsigned short* __restrict__ Vt) {
  __shared__ __align__(16) unsigned short As[128 * 64];
  __shared__ __align__(16) unsigned short Bs[128 * 64];
  int t = threadIdx.x;
  int w = t >> 6, l = t & 63;
  int lane16 = l & 15, lhi = l >> 4;
  int mbase = blockIdx.y * 128, nbase = blockIdx.x * 128;
  int wm = (w >> 1) * 64, wn = (w & 1) * 64;

  const int srow = t >> 3;                       /* 0..31 */
  const int sslot = (t & 7) ^ ((t >> 3) & 7);    /* 3-bit key = row&7 */
  const unsigned short* Ag = A + (size_t)(mbase + srow) * 1024 + sslot * 8;
  const unsigned short* Bg = Bt + (size_t)(nbase + srow) * 1024 + sslot * 8;

  const int sl0 = ((lhi ^ (lane16 & 7)) << 4);
  const char* Ard = (const char*)As + (wm + lane16) * 128;
  const char* Brd = (const char*)Bs + (wn + lane16) * 128;

  f32x4 acc[4][4];
  f32x4 z4 = {0.f, 0.f, 0.f, 0.f};
#pragma unroll
  for (int i = 0; i < 4; ++i)
#pragma unroll
    for (int j = 0; j < 4; ++j) acc[i][j] = z4;

  for (int kt = 0; kt < 1024; kt += 64) {
#pragma unroll
    for (int i = 0; i < 4; ++i) {
      GLDS16(Ag + (size_t)(i * 32) * 1024 + kt, (char*)As + i * 4096 + w * 1024);
      GLDS16(Bg + (size_t)(i * 32) * 1024 + kt, (char*)Bs + i * 4096 + w * 1024);
    }
    __syncthreads();
#pragma unroll
    for (int kh = 0; kh < 2; ++kh) {
      const int so = sl0 ^ (kh << 6);
      bf16x8 af[4], bfr[4];
#pragma unroll
      for (int mi = 0; mi < 4; ++mi)
        af[mi] = *(const bf16x8*)(Ard + mi * 2048 + so);
#pragma unroll
      for (int ni = 0; ni < 4; ++ni)
        bfr[ni] = *(const bf16x8*)(Brd + ni * 2048 + so);
#pragma unroll
      for (int mi = 0; mi < 4; ++mi)
#pragma unroll
        for (int ni = 0; ni < 4; ++ni)
          acc[mi][ni] = MFMA16(af[mi], bfr[ni], acc[mi][ni]);
    }
    __syncthreads();
  }

#pragma unroll
  for (int mi = 0; mi < 4; ++mi) {
#pragma unroll
    for (int ni = 0; ni < 4; ++ni) {
      const int gcol = nbase + wn + ni * 16 + lane16;
      if (gcol < 2048) {
#pragma unroll
        for (int r = 0; r < 4; ++r) {
          int grow = mbase + wm + mi * 16 + (lhi << 2) + r;
          int b = grow >> 11, s = grow & 2047;
          unsigned short val = f2bf(acc[mi][ni][r]);
          if (gcol < 1024) {
            int h = gcol >> 6, d = gcol & 63;
            Qb[((size_t)(b * 16 + h) * 2048 + s) * 64 + d] = val;
          } else {
            int n2 = gcol - 1024;
            int h = n2 >> 6, d = n2 & 63;
            Kb[((size_t)(b * 16 + h) * 2048 + s) * 64 + d] = val;
          }
        }
      } else {
        int grow0 = mbase + wm + mi * 16 + (lhi << 2);
        int b = grow0 >> 11, s = grow0 & 2047;
        int n2 = gcol - 2048;
        int h = n2 >> 6, d = n2 & 63;
        ushort4 v4;
        v4.x = f2bf(acc[mi][ni][0]);
        v4.y = f2bf(acc[mi][ni][1]);
        v4.z = f2bf(acc[mi][ni][2]);
        v4.w = f2bf(acc[mi][ni][3]);
        *(ushort4*)&Vt[((size_t)(b * 16 + h) * 64 + d) * 2048 + s] = v4;
      }
    }
  }
}

/* ---------------- flash attention (r14 proven best) ---------------------
   grid 512 blocks (XCD-chunk swizzled), 512 threads = 8 waves.
   Block: 256 q-rows of one (b,h); wave: 32 q-rows. KVBLK = 64.
   K/V staged via global_load_lds, double-buffered, 3-bit XOR swizzle
   (both-sides). Ps [8][32][64] exact-128B rows, same XOR write+read.
   Static-max softmax: p = exp2(s*SM_C - 16).
   NOTE (r15 lesson): do NOT hoist V ds_reads before the Ps ds_writes —
   LDS queue is FIFO, lengthening the pa-read lgkmcnt wait (−3 us). */

__global__ __launch_bounds__(512, 4)
void attn_kernel(const unsigned short* __restrict__ Qb,
                 const unsigned short* __restrict__ Kb,
                 const unsigned short* __restrict__ Vt,
                 unsigned short* __restrict__ attn) {
  __shared__ __align__(16) unsigned short Ks[2][4096]; /* [64 rows][128B] swz */
  __shared__ __align__(16) unsigned short Vs[2][4096]; /* [64 drows][128B] swz */
  __shared__ __align__(16) unsigned short Ps[8][32][64]; /* swizzled rows */

  const int t = threadIdx.x, wv = t >> 6, l = t & 63;
  const int lane16 = l & 15, lhi = l >> 4;

  /* bijective XCD-chunk swizzle: 512 blocks, 8 XCDs, 64 per chunk */
  const int bid = blockIdx.x;
  const int nid = (bid & 7) * 64 + (bid >> 3);
  const int qg = nid & 7, h = (nid >> 3) & 15, b = nid >> 7;

  const unsigned short* Qp = Qb + (size_t)(b * NHEADS + h) * SEQ * HD;
  const unsigned short* Kp = Kb + (size_t)(b * NHEADS + h) * SEQ * HD;
  const unsigned short* Vp = Vt + (size_t)(b * NHEADS + h) * HD * SEQ;

  const int q0 = qg * 256 + wv * 32;

  bf16x8 qa[2][2];
#pragma unroll
  for (int mi = 0; mi < 2; ++mi)
#pragma unroll
    for (int kh = 0; kh < 2; ++kh)
      qa[mi][kh] = *(const bf16x8*)(Qp + (size_t)(q0 + mi * 16 + lane16) * HD +
                                    kh * 32 + lhi * 8);

  const int srow = t >> 3; /* 0..63 */
  const unsigned short* kg = Kp + srow * HD + (((t & 7) ^ ((t >> 5) & 7)) * 8);
  const unsigned short* vg =
      Vp + (size_t)srow * SEQ + (((t & 7) ^ ((t >> 3) & 7)) * 8);

  const int key = lane16 & 7;
  const int off0 = (lhi ^ key) << 4;
  const int off1 = off0 ^ 64;
  const char* krd = (const char*)&Ks[0][0] + lane16 * 512;
  const char* vrd = (const char*)&Vs[0][0] + lane16 * 128;

  /* Ps addressing (swizzled): write base half-slot, read slot key */
  char* psbase = (char*)&Ps[wv][0][0];
  const int wsl = ((lane16 >> 1) << 4) + ((lane16 & 1) << 3);
  const int rsl = key << 4;

  f32x4 z4 = {0.f, 0.f, 0.f, 0.f};
  f32x4 o[2][4];
  float lsum[2][4];
#pragma unroll
  for (int mi = 0; mi < 2; ++mi)
#pragma unroll
    for (int nd = 0; nd < 4; ++nd) o[mi][nd] = z4;
#pragma unroll
  for (int mi = 0; mi < 2; ++mi)
#pragma unroll
    for (int r = 0; r < 4; ++r) lsum[mi][r] = 0.f;

  GLDS16(kg, (char*)&Ks[0][0] + wv * 1024);
  GLDS16(vg, (char*)&Vs[0][0] + wv * 1024);
  __syncthreads();

  int cur = 0;
  for (int ti = 0; ti < SEQ / 64; ++ti) {
    if (ti < SEQ / 64 - 1) {
      const int kb = (ti + 1) * 64;
      GLDS16(kg + (size_t)kb * HD, (char*)&Ks[cur ^ 1][0] + wv * 1024);
      GLDS16(vg + kb, (char*)&Vs[cur ^ 1][0] + wv * 1024);
    }

    /* ---- QK^T ---- */
    const char* kp = krd + cur * 8192;
    bf16x8 kf[4][2];
#pragma unroll
    for (int ni = 0; ni < 4; ++ni) {
      kf[ni][0] = *(const bf16x8*)(kp + ni * 128 + off0);
      kf[ni][1] = *(const bf16x8*)(kp + ni * 128 + off1);
    }
#pragma unroll
    for (int mi = 0; mi < 2; ++mi) {
      f32x4 s[4];
#pragma unroll
      for (int ni = 0; ni < 4; ++ni) {
        f32x4 a = MFMA16(qa[mi][0], kf[ni][0], z4);
        s[ni] = MFMA16(qa[mi][1], kf[ni][1], a);
      }
#pragma unroll
      for (int r = 0; r < 4; ++r) {
        float p0 = exp2_hw(__builtin_fmaf(s[0][r], SM_C, -SMAX));
        float p1 = exp2_hw(__builtin_fmaf(s[1][r], SM_C, -SMAX));
        float p2 = exp2_hw(__builtin_fmaf(s[2][r], SM_C, -SMAX));
        float p3 = exp2_hw(__builtin_fmaf(s[3][r], SM_C, -SMAX));
        lsum[mi][r] += (p0 + p1) + (p2 + p3);
        bf16x4 pk;
        pk[0] = (__bf16)p0; pk[1] = (__bf16)p1;
        pk[2] = (__bf16)p2; pk[3] = (__bf16)p3;
        const int row = mi * 16 + (lhi << 2) + r;
        const int rk = ((lhi << 2) + r) & 7;
        *(bf16x4*)(psbase + row * 128 + (wsl ^ (rk << 4))) = pk;
      }
    }

    /* ---- PV ---- */
    bf16x8 pa[2][2];
#pragma unroll
    for (int mi = 0; mi < 2; ++mi)
#pragma unroll
      for (int kvh = 0; kvh < 2; ++kvh)
        pa[mi][kvh] = *(const bf16x8*)(psbase + (mi * 16 + lane16) * 128 +
                                       ((((kvh << 2) | lhi) << 4) ^ rsl));
    const char* vp2 = vrd + cur * 8192;
#pragma unroll
    for (int nd = 0; nd < 4; ++nd) {
      bf16x8 v0 = *(const bf16x8*)(vp2 + nd * 2048 + off0);
      bf16x8 v1 = *(const bf16x8*)(vp2 + nd * 2048 + off1);
#pragma unroll
      for (int mi = 0; mi < 2; ++mi) {
        o[mi][nd] = MFMA16(pa[mi][0], v0, o[mi][nd]);
        o[mi][nd] = MFMA16(pa[mi][1], v1, o[mi][nd]);
      }
    }
    __syncthreads();
    cur ^= 1;
  }

#pragma unroll
  for (int mi = 0; mi < 2; ++mi)
#pragma unroll
    for (int r = 0; r < 4; ++r) {
      float ls = lsum[mi][r];
      ls += __shfl_xor(ls, 1);
      ls += __shfl_xor(ls, 2);
      ls += __shfl_xor(ls, 4);
      ls += __shfl_xor(ls, 8);
      lsum[mi][r] = 1.0f / ls;
    }
  size_t orow_base = (size_t)b * SEQ;
#pragma unroll
  for (int mi = 0; mi < 2; ++mi)
#pragma unroll
    for (int nd = 0; nd < 4; ++nd)
#pragma unroll
      for (int r = 0; r < 4; ++r) {
        int row = q0 + mi * 16 + (lhi << 2) + r;
        attn[(orow_base + row) * DIM + h * HD + nd * 16 + lane16] =
            f2bf(o[mi][nd][r] * lsum[mi][r]);
      }
}

/* ---------------- out projection: out = A(8192x1024)*Bt(1024x1024)^T + bias */

__global__ __launch_bounds__(256, 3)
void gemm_proj_kernel(const unsigned short* __restrict__ A,
                      const unsigned short* __restrict__ Bt,
                      const float* __restrict__ bias,
                      float* __restrict__ out) {
  __shared__ __align__(16) unsigned short Asp[128 * 64];
  __shared__ __align__(16) unsigned short Bsp[128 * 64];
  int t = threadIdx.x;
  int w = t >> 6, l = t & 63;
  int lane16 = l & 15, lhi = l >> 4;
  int mbase = blockIdx.y * 128, nbase = blockIdx.x * 128;
  int wm = (w >> 1) * 64, wn = (w & 1) * 64;

  const int srow = t >> 3;
  const int sslot = (t & 7) ^ ((t >> 3) & 7);
  const unsigned short* Ag = A + (size_t)(mbase + srow) * 1024 + sslot * 8;
  const unsigned short* Bg = Bt + (size_t)(nbase + srow) * 1024 + sslot * 8;

  const int sl0 = ((lhi ^ (lane16 & 7)) << 4);
  const char* Ard = (const char*)Asp + (wm + lane16) * 128;
  const char* Brd = (const char*)Bsp + (wn + lane16) * 128;

  f32x4 acc[4][4];
  f32x4 z4 = {0.f, 0.f, 0.f, 0.f};
#pragma unroll
  for (int i = 0; i < 4; ++i)
#pragma unroll
    for (int j = 0; j < 4; ++j) acc[i][j] = z4;

  for (int kt = 0; kt < 1024; kt += 64) {
#pragma unroll
    for (int i = 0; i < 4; ++i) {
      GLDS16(Ag + (size_t)(i * 32) * 1024 + kt, (char*)Asp + i * 4096 + w * 1024);
      GLDS16(Bg + (size_t)(i * 32) * 1024 + kt, (char*)Bsp + i * 4096 + w * 1024);
    }
    __syncthreads();
#pragma unroll
    for (int kh = 0; kh < 2; ++kh) {
      const int so = sl0 ^ (kh << 6);
      bf16x8 af[4], bfr[4];
#pragma unroll
      for (int mi = 0; mi < 4; ++mi)
        af[mi] = *(const bf16x8*)(Ard + mi * 2048 + so);
#pragma unroll
      for (int ni = 0; ni < 4; ++ni)
        bfr[ni] = *(const bf16x8*)(Brd + ni * 2048 + so);
#pragma unroll
      for (int mi = 0; mi < 4; ++mi)
#pragma unroll
        for (int ni = 0; ni < 4; ++ni)
          acc[mi][ni] = MFMA16(af[mi], bfr[ni], acc[mi][ni]);
    }
    __syncthreads();
  }

#pragma unroll
  for (int mi = 0; mi < 4; ++mi) {
#pragma unroll
    for (int ni = 0; ni < 4; ++ni) {
#pragma unroll
      for (int r = 0; r < 4; ++r) {
        int grow = mbase + wm + mi * 16 + (lhi << 2) + r;
        int gcol = nbase + wn + ni * 16 + lane16;
        out[(size_t)grow * 1024 + gcol] = acc[mi][ni][r] + bias[gcol];
      }
    }
  }
}

/* ---------------- launch ---------------- */

extern "C" void kernel_launch(void* const* d_in, const int* in_sizes, int n_in,
                              void* d_out, int out_size, void* d_ws,
                              size_t ws_size, hipStream_t stream) {
  const float* x = (const float*)d_in[0];
  const float* w_qkv = (const float*)d_in[1];
  const float* w_proj = (const float*)d_in[2];
  const float* b_proj = (const float*)d_in[3];
  float* out = (float*)d_out;
  char* ws = (char*)d_ws;

  unsigned short* xb = (unsigned short*)(ws);
  unsigned short* attnb = (unsigned short*)(ws);
  unsigned short* wqkvT = (unsigned short*)(ws + (16ull << 20));
  unsigned short* wprojT = (unsigned short*)(ws + (22ull << 20));
  unsigned short* Qb = (unsigned short*)(ws + (24ull << 20));
  unsigned short* Kb = (unsigned short*)(ws + (40ull << 20));
  unsigned short* Vt = (unsigned short*)(ws + (56ull << 20));

  prep_kernel<<<12288, 256, 0, stream>>>(x, xb, w_qkv, wqkvT, w_proj, wprojT);
  gemm_qkv_kernel<<<dim3(N3 / 128, MROWS / 128), 256, 0, stream>>>(xb, wqkvT, Qb, Kb, Vt);
  attn_kernel<<<512, 512, 0, stream>>>(Qb, Kb, Vt, attnb);
  gemm_proj_kernel<<<dim3(DIM / 128, MROWS / 128), 256, 0, stream>>>(attnb, wprojT, b_proj, out);
}